// Round 1
// baseline (126.057 us; speedup 1.0000x reference)
//
#include <hip/hip_runtime.h>
#include <hip/hip_bf16.h>

// B=8, C=64, O=64, H=W=128, stride=1, pad=1, 3x3.
constexpr int Bc = 8;
constexpr int Cc = 64;
constexpr int Oc = 64;
constexpr int Hc = 128;
constexpr int Wc = 128;
constexpr int HWc = Hc * Wc;
constexpr int CP = 72;   // padded LDS row stride in bf16 elems (144 B)

typedef __attribute__((ext_vector_type(8))) short short8;   // 8 x bf16 (4 VGPRs)
typedef __attribute__((ext_vector_type(4))) float floatx4;

// One block per (b,h) row, 512 threads = 8 waves.
// v2 changes vs 106us baseline:
//  - XCD-locality remap: b = blk&7 (== empirical XCD id), h = blk>>3. Each XCD
//    processes one image with ascending h -> rows h-1/h/h+1 reused in its L2.
//  - Phase 1 rewritten as float4 strips: thread owns (4-wide w-strip x 4
//    consecutive channels). 9 load instrs per channel cover 4 pixels
//    (vs 9 per pixel): VMEM instrs 144 -> 36 per thread, 2x fewer tap bytes.
//  - Padding handled by zeroing tap VALUES (correct for both agg and div).
__global__ __launch_bounds__(512) void spconv_kernel(
    const float* __restrict__ x, const float* __restrict__ core,
    const float* __restrict__ peri, const float* __restrict__ thr,
    const float* __restrict__ scl, float* __restrict__ out)
{
    __shared__ __hip_bfloat16 s_selT[Wc][CP];   // [w][c] 18432 B
    __shared__ __hip_bfloat16 s_core[Oc][CP];   // [o][c]  9216 B
    __shared__ float s_divp[16][132];           //          8448 B (+4 pad: bank spread)
    __shared__ float s_msk[Wc];                 //           512 B

    const int tid = threadIdx.x;
    const int blk = blockIdx.x;
    const int b   = blk & 7;                    // one image per XCD
    const int h   = blk >> 3;

    // ---- Phase 0: core -> bf16 LDS (4096 elems / 512 thr = 8 each) ----
    #pragma unroll
    for (int i = 0; i < 8; ++i) {
        const int idx = i * 512 + tid;
        s_core[idx >> 6][idx & 63] = __float2bfloat16(core[idx]);
    }

    // ---- Phase 1: taps, float4 strips ----
    // thread -> (strip s of 4 w, group cg of 4 consecutive channels)
    const int cg = tid & 15;                    // channel group: c0..c0+3
    const int s  = tid >> 4;                    // w strip: w0..w0+3
    const int w0 = s * 4;
    const int c0 = cg * 4;

    const float* xb = x + (size_t)b * Cc * HWc + (size_t)h * Wc;

    // block-uniform h masks / offsets; lane-uniform w masks / clamped offsets
    const float mU = (h > 0)      ? 1.f : 0.f;
    const float mD = (h < Hc - 1) ? 1.f : 0.f;
    const int   dU = (h > 0)      ? -Wc : 0;
    const int   dD = (h < Hc - 1) ?  Wc : 0;
    const float mL = (s > 0)  ? 1.f : 0.f;
    const float mR = (s < 31) ? 1.f : 0.f;
    const int   oL = (s > 0)  ? (w0 - 1) : w0;        // clamped, value masked
    const int   oR = (s < 31) ? (w0 + 4) : (w0 + 3);
    const float mUL = mU * mL, mUR = mU * mR;
    const float mDL = mD * mL, mDR = mD * mR;

    const float p0 = peri[0], p1 = peri[1], p2 = peri[2], p3 = peri[3];
    const float p4 = peri[4], p5 = peri[5], p6 = peri[6], p7 = peri[7];

    float dv[4] = {0.f, 0.f, 0.f, 0.f};

    #pragma unroll
    for (int ci = 0; ci < 4; ++ci) {
        const float* rc = xb + (size_t)(c0 + ci) * HWc;  // row h
        const float* ru = rc + dU;                       // row h-1 (clamped)
        const float* rd = rc + dD;                       // row h+1 (clamped)

        const floatx4 c4 = *(const floatx4*)(rc + w0);
        const floatx4 u4 = *(const floatx4*)(ru + w0);
        const floatx4 d4 = *(const floatx4*)(rd + w0);

        // 6-wide tap windows [w0-1 .. w0+4], padded taps zeroed
        float U[6]  = { ru[oL] * mUL, u4[0] * mU, u4[1] * mU,
                        u4[2] * mU,   u4[3] * mU, ru[oR] * mUR };
        float Cv[6] = { rc[oL] * mL,  c4[0], c4[1],
                        c4[2],        c4[3], rc[oR] * mR };
        float D[6]  = { rd[oL] * mDL, d4[0] * mD, d4[1] * mD,
                        d4[2] * mD,   d4[3] * mD, rd[oR] * mDR };

        #pragma unroll
        for (int j = 0; j < 4; ++j) {
            const float t = Cv[j + 1];                 // center tap
            // agg: PERI_IDX order (-1,-1),(-1,0),(-1,1),(0,-1),(0,1),(1,-1),(1,0),(1,1)
            float agg =      p0 * U[j];
            agg = fmaf(p1, U[j + 1],  agg);
            agg = fmaf(p2, U[j + 2],  agg);
            agg = fmaf(p3, Cv[j],     agg);
            agg = fmaf(p4, Cv[j + 2], agg);
            agg = fmaf(p5, D[j],      agg);
            agg = fmaf(p6, D[j + 1],  agg);
            agg = fmaf(p7, D[j + 2],  agg);
            s_selT[w0 + j][c0 + ci] = __float2bfloat16(agg);  // 2-way bank, free

            float e, dd;
            e = U[j] - t;      dd = e * e;
            e = U[j + 1] - t;  dd = fmaf(e, e, dd);
            e = U[j + 2] - t;  dd = fmaf(e, e, dd);
            e = Cv[j] - t;     dd = fmaf(e, e, dd);
            e = Cv[j + 2] - t; dd = fmaf(e, e, dd);
            e = D[j] - t;      dd = fmaf(e, e, dd);
            e = D[j + 1] - t;  dd = fmaf(e, e, dd);
            e = D[j + 2] - t;  dd = fmaf(e, e, dd);
            dv[j] += dd;
        }
    }
    {
        floatx4 dvv = { dv[0], dv[1], dv[2], dv[3] };
        *(floatx4*)&s_divp[cg][w0] = dvv;              // aligned b128 write
    }
    __syncthreads();

    // ---- Phase 2: mask + sel fixup ----
    if (tid < Wc) {
        float div = 0.f;
        #pragma unroll
        for (int g = 0; g < 16; ++g) div += s_divp[g][tid];
        s_msk[tid] = (((div - thr[0]) * scl[0]) > 0.f) ? 1.f : 0.f;
    }
    __syncthreads();

    #pragma unroll
    for (int i = 0; i < 16; ++i) {                // 8192 elems / 512 thr
        const int idx = i * 512 + tid;
        const int ww  = idx & (Wc - 1);
        const int c   = idx >> 7;
        if (s_msk[ww] == 0.f)                     // rare: div >> thr usually
            s_selT[ww][c] = __float2bfloat16(xb[(size_t)c * HWc + ww]);
    }
    __syncthreads();

    // ---- Phase 3: MFMA GEMM: D[o][w] = core[o][c] * sel[c][w], K=64 ----
    const int lane = tid & 63;
    const int wid  = tid >> 6;          // 0..7
    const int o0   = (wid & 3) * 16;    // o-tile
    const int wh   = wid >> 2;          // w-half 0/1 -> 4 w-tiles each
    const int n    = lane & 15;         // col within tile (w), also A-row (o)
    const int quad = lane >> 4;

    // A-fragment: A[m=lane&15][k=quad*8+j], contiguous 8 bf16 -> b128 loads
    const short8 a0 = *(const short8*)&s_core[o0 + n][quad * 8];
    const short8 a1 = *(const short8*)&s_core[o0 + n][quad * 8 + 32];

    float* outb = out + ((size_t)(b * Oc) * Hc + h) * Wc;

    #pragma unroll
    for (int t = 0; t < 4; ++t) {
        const int wt0 = (wh * 4 + t) * 16;
        // B-fragment: B[k=quad*8+j][n=lane&15]  (s_selT is [w][c] = B^T rows)
        const short8 b0 = *(const short8*)&s_selT[wt0 + n][quad * 8];
        const short8 b1 = *(const short8*)&s_selT[wt0 + n][quad * 8 + 32];
        floatx4 acc = {0.f, 0.f, 0.f, 0.f};
        acc = __builtin_amdgcn_mfma_f32_16x16x32_bf16(a0, b0, acc, 0, 0, 0);
        acc = __builtin_amdgcn_mfma_f32_16x16x32_bf16(a1, b1, acc, 0, 0, 0);
        // D: col = lane&15 (w), row = quad*4 + r (o)
        #pragma unroll
        for (int r = 0; r < 4; ++r) {
            const int o = o0 + quad * 4 + r;
            outb[(size_t)o * HWc + wt0 + n] = acc[r];
        }
    }
}

extern "C" void kernel_launch(void* const* d_in, const int* in_sizes, int n_in,
                              void* d_out, int out_size, void* d_ws, size_t ws_size,
                              hipStream_t stream) {
    const float* x    = (const float*)d_in[0];
    const float* core = (const float*)d_in[1];
    const float* peri = (const float*)d_in[2];
    const float* thr  = (const float*)d_in[3];
    const float* scl  = (const float*)d_in[4];
    float* out = (float*)d_out;

    spconv_kernel<<<dim3(Bc * Hc), dim3(512), 0, stream>>>(
        x, core, peri, thr, scl, out);
}

// Round 2
// 102.941 us; speedup vs baseline: 1.2246x; 1.2246x over previous
//
#include <hip/hip_runtime.h>
#include <hip/hip_bf16.h>

// B=8, C=64, O=64, H=W=128, stride=1, pad=1, 3x3.
constexpr int Bc = 8;
constexpr int Cc = 64;
constexpr int Oc = 64;
constexpr int Hc = 128;
constexpr int Wc = 128;
constexpr int HWc = Hc * Wc;
constexpr int CP = 72;   // padded LDS row stride in bf16 elems (144 B: 16B-aligned, bank-stride 4)

typedef __attribute__((ext_vector_type(8))) short short8;   // 8 x bf16 (4 VGPRs)
typedef __attribute__((ext_vector_type(4))) float floatx4;

// One block per (b,h) row, 512 threads = 8 waves.
// v3 = round-0 verified structure (Phase 1 per-pixel, fully wave-coalesced
//      256B/instr loads — measured fastest) + two additions:
//  - XCD-locality remap: b = blk&7 (blockIdx%8 == XCD id), h = blk>>3.
//    Each XCD streams one 4MB image with ascending h -> taps of rows
//    h-1/h/h+1 hit that XCD's private L2. (v2 measured FETCH 16.5MB < 32MB.)
//  - s_any: block-uniform skip of the Phase-2 fixup loop (mask==0 is
//    measure-zero for this distribution: E[div]~1e3 >> thr=0.1). Removes
//    16 serialized LDS-read+branch iters/thread and one barrier.
__global__ __launch_bounds__(512) void spconv_kernel(
    const float* __restrict__ x, const float* __restrict__ core,
    const float* __restrict__ peri, const float* __restrict__ thr,
    const float* __restrict__ scl, float* __restrict__ out)
{
    __shared__ __hip_bfloat16 s_selT[Wc][CP];   // [w][c] 18432 B
    __shared__ __hip_bfloat16 s_core[Oc][CP];   // [o][c]  9216 B
    __shared__ float s_divp[4][Wc];             //          2048 B
    __shared__ float s_msk[Wc];                 //           512 B
    __shared__ int   s_any;                     // any masked pixel in this row?

    const int tid = threadIdx.x;
    const int w   = tid & (Wc - 1);
    const int q   = tid >> 7;                   // channel quarter 0..3
    const int b   = blockIdx.x & 7;             // one image per XCD
    const int h   = blockIdx.x >> 3;

    if (tid == 0) s_any = 0;

    // ---- Phase 0: core -> bf16 LDS (4096 elems / 512 thr = 8 each) ----
    #pragma unroll
    for (int i = 0; i < 8; ++i) {
        const int idx = i * 512 + tid;
        s_core[idx >> 6][idx & 63] = __float2bfloat16(core[idx]);
    }

    // ---- Phase 1: taps ----
    const float* xb = x + (size_t)b * Cc * HWc + (size_t)h * Wc;

    // PERI_IDX taps: [0,1,2,3,5,6,7,8] -> (dh,dw)
    const int   dh[8] = {-1,-1,-1, 0, 0, 1, 1, 1};
    const int   dw[8] = {-1, 0, 1,-1, 1,-1, 0, 1};
    int   off[8];
    float pl[8], mf[8];
    #pragma unroll
    for (int k = 0; k < 8; ++k) {
        const bool okh = (h + dh[k] >= 0) && (h + dh[k] < Hc);
        const bool okw = (w + dw[k] >= 0) && (w + dw[k] < Wc);
        const bool ok  = okh && okw;
        off[k] = ok ? (w + dh[k] * Wc + dw[k]) : w;   // clamp to a safe addr
        mf[k]  = ok ? 1.f : 0.f;
        pl[k]  = ok ? peri[k] : 0.f;                  // pre-masked weight
    }

    float divacc = 0.f;
    const float* rowq = xb + (size_t)(q * 16) * HWc;
    #pragma unroll 4
    for (int ci = 0; ci < 16; ++ci) {
        const float* row = rowq + (size_t)ci * HWc;
        const float t4 = row[w];
        float v[8];
        #pragma unroll
        for (int k = 0; k < 8; ++k) v[k] = row[off[k]];
        float agg = 0.f;
        #pragma unroll
        for (int k = 0; k < 8; ++k) agg = fmaf(pl[k], v[k], agg);
        s_selT[w][q * 16 + ci] = __float2bfloat16(agg);
        #pragma unroll
        for (int k = 0; k < 8; ++k) {
            const float d = fmaf(mf[k], v[k], -t4);   // padded tap: 0 - center
            divacc = fmaf(d, d, divacc);
        }
    }
    s_divp[q][w] = divacc;
    __syncthreads();

    // ---- Phase 2: mask ----
    if (tid < Wc) {
        const float div = s_divp[0][tid] + s_divp[1][tid]
                        + s_divp[2][tid] + s_divp[3][tid];
        const bool one = ((div - thr[0]) * scl[0]) > 0.f;  // == sigmoid>0.5
        s_msk[tid] = one ? 1.f : 0.f;
        if (!one) s_any = 1;                  // benign LDS race: all write 1
    }
    __syncthreads();

    // ---- Rare path: overwrite masked columns with center ----
    if (s_any) {                              // block-uniform branch
        #pragma unroll
        for (int i = 0; i < 16; ++i) {        // 8192 elems / 512 thr
            const int idx = i * 512 + tid;
            const int ww  = idx & (Wc - 1);
            const int c   = idx >> 7;
            if (s_msk[ww] == 0.f)
                s_selT[ww][c] = __float2bfloat16(xb[(size_t)c * HWc + ww]);
        }
        __syncthreads();
    }

    // ---- Phase 3: MFMA GEMM: D[o][w] = core[o][c] * sel[c][w], K=64 ----
    const int lane = tid & 63;
    const int wid  = tid >> 6;          // 0..7
    const int o0   = (wid & 3) * 16;    // o-tile
    const int wh   = wid >> 2;          // w-half 0/1 -> 4 w-tiles each
    const int n    = lane & 15;         // col within tile (w), also A-row (o)
    const int quad = lane >> 4;

    // A-fragment: A[m=lane&15][k=quad*8+j], contiguous 8 bf16 -> b128 loads
    const short8 a0 = *(const short8*)&s_core[o0 + n][quad * 8];
    const short8 a1 = *(const short8*)&s_core[o0 + n][quad * 8 + 32];

    float* outb = out + ((size_t)(b * Oc) * Hc + h) * Wc;

    #pragma unroll
    for (int t = 0; t < 4; ++t) {
        const int w0 = (wh * 4 + t) * 16;
        // B-fragment: B[k=quad*8+j][n=lane&15]  (s_selT is [w][c] = B^T rows)
        const short8 b0 = *(const short8*)&s_selT[w0 + n][quad * 8];
        const short8 b1 = *(const short8*)&s_selT[w0 + n][quad * 8 + 32];
        floatx4 acc = {0.f, 0.f, 0.f, 0.f};
        acc = __builtin_amdgcn_mfma_f32_16x16x32_bf16(a0, b0, acc, 0, 0, 0);
        acc = __builtin_amdgcn_mfma_f32_16x16x32_bf16(a1, b1, acc, 0, 0, 0);
        // D: col = lane&15 (w), row = quad*4 + r (o)
        #pragma unroll
        for (int r = 0; r < 4; ++r) {
            const int o = o0 + quad * 4 + r;
            outb[(size_t)o * HWc + w0 + n] = acc[r];
        }
    }
}

extern "C" void kernel_launch(void* const* d_in, const int* in_sizes, int n_in,
                              void* d_out, int out_size, void* d_ws, size_t ws_size,
                              hipStream_t stream) {
    const float* x    = (const float*)d_in[0];
    const float* core = (const float*)d_in[1];
    const float* peri = (const float*)d_in[2];
    const float* thr  = (const float*)d_in[3];
    const float* scl  = (const float*)d_in[4];
    float* out = (float*)d_out;

    spconv_kernel<<<dim3(Bc * Hc), dim3(512), 0, stream>>>(
        x, core, peri, thr, scl, out);
}

// Round 3
// 100.495 us; speedup vs baseline: 1.2544x; 1.0243x over previous
//
#include <hip/hip_runtime.h>
#include <hip/hip_bf16.h>

// B=8, C=64, O=64, H=W=128, stride=1, pad=1, 3x3.
constexpr int Bc = 8;
constexpr int Cc = 64;
constexpr int Oc = 64;
constexpr int Hc = 128;
constexpr int Wc = 128;
constexpr int HWc = Hc * Wc;
constexpr int CP = 72;   // padded LDS row stride in bf16 elems (144 B)

typedef __attribute__((ext_vector_type(8))) short short8;   // 8 x bf16 (4 VGPRs)
typedef __attribute__((ext_vector_type(4))) float floatx4;

// v4: TWO output rows per block (grid 512 = exactly 2 blocks/CU resident ->
// zero generational turnover; v3's 1024 blocks ran as 4 latency-bound
// generations). Vertical tap reuse: rows h0-1..h0+2 loaded once serve both
// output rows: 12 loads / 2 pixels = 6/pixel vs 9. All loads remain
// per-pixel wave-coalesced (v1/v3-proven pattern). Keeps XCD remap (b=blk&7,
// measured FETCH 16.5MB < 32MB input) and s_any fixup skip.
__global__ __launch_bounds__(512, 4) void spconv_kernel(
    const float* __restrict__ x, const float* __restrict__ core,
    const float* __restrict__ peri, const float* __restrict__ thr,
    const float* __restrict__ scl, float* __restrict__ out)
{
    __shared__ __hip_bfloat16 s_selT[2][Wc][CP];  // [row][w][c] 36864 B
    __shared__ __hip_bfloat16 s_core[Oc][CP];     // [o][c]       9216 B
    __shared__ float s_divp[2][4][Wc];            //              4096 B
    __shared__ float s_msk[2][Wc];                //              1024 B
    __shared__ int   s_any;

    const int tid = threadIdx.x;
    const int w   = tid & (Wc - 1);
    const int q   = tid >> 7;                   // channel quarter 0..3
    const int b   = blockIdx.x & 7;             // one image per XCD
    const int hp  = blockIdx.x >> 3;            // row pair 0..63
    const int h0  = hp * 2;

    if (tid == 0) s_any = 0;

    // ---- Phase 0: core -> bf16 LDS (4096 elems / 512 thr = 8 each) ----
    #pragma unroll
    for (int i = 0; i < 8; ++i) {
        const int idx = i * 512 + tid;
        s_core[idx >> 6][idx & 63] = __float2bfloat16(core[idx]);
    }

    // ---- Phase 1: taps for output rows h0 and h0+1 ----
    const float* xb = x + (size_t)b * Cc * HWc + (size_t)h0 * Wc;

    // vertical masks/offsets (block-uniform); h0 in [0,126], h0+1 <= 127
    const float mU  = (h0 > 0) ? 1.f : 0.f;        // row h0-1 valid
    const float mD2 = (h0 < Hc - 2) ? 1.f : 0.f;   // row h0+2 valid
    const int   dU  = (h0 > 0) ? -Wc : 0;          // clamped
    const int   dD2 = (h0 < Hc - 2) ? 2 * Wc : Wc; // clamped
    // horizontal masks/offsets (lane-dependent)
    const float mL = (w > 0) ? 1.f : 0.f;
    const float mR = (w < Wc - 1) ? 1.f : 0.f;
    const int   oL = (w > 0) ? w - 1 : w;
    const int   oR = (w < Wc - 1) ? w + 1 : w;
    const float mUL = mU * mL,  mUR = mU * mR;
    const float mDL = mD2 * mL, mDR = mD2 * mR;

    const float p0 = peri[0], p1 = peri[1], p2 = peri[2], p3 = peri[3];
    const float p4 = peri[4], p5 = peri[5], p6 = peri[6], p7 = peri[7];

    float dvA = 0.f, dvB = 0.f;
    const float* rowq = xb + (size_t)(q * 16) * HWc;
    #pragma unroll 4
    for (int ci = 0; ci < 16; ++ci) {
        const float* r0 = rowq + (size_t)ci * HWc;   // row h0
        const float* rm = r0 + dU;                   // row h0-1 (clamped)
        const float* r1 = r0 + Wc;                   // row h0+1 (always valid)
        const float* r2 = r0 + dD2;                  // row h0+2 (clamped)

        float ul = rm[oL], uc = rm[w], ur = rm[oR];
        float cl = r0[oL], cc = r0[w], cr = r0[oR];
        float dl = r1[oL], dc = r1[w], dr = r1[oR];
        float el = r2[oL], ec = r2[w], er = r2[oR];

        // zero padded taps (correct for both agg and div: (0-t)^2 = t^2)
        ul *= mUL; uc *= mU;  ur *= mUR;
        const float clm = cl * mL, crm = cr * mR;
        const float dlm = dl * mL, drm = dr * mR;
        el *= mDL; ec *= mD2; er *= mDR;

        // --- output row A = h0: center cc; taps U=(ul,uc,ur) C=(clm,crm) D=(dlm,dc,drm)
        float aggA =     p0 * ul;
        aggA = fmaf(p1, uc,  aggA);
        aggA = fmaf(p2, ur,  aggA);
        aggA = fmaf(p3, clm, aggA);
        aggA = fmaf(p4, crm, aggA);
        aggA = fmaf(p5, dlm, aggA);
        aggA = fmaf(p6, dc,  aggA);
        aggA = fmaf(p7, drm, aggA);
        s_selT[0][w][q * 16 + ci] = __float2bfloat16(aggA);

        float e_;
        e_ = ul  - cc; dvA = fmaf(e_, e_, dvA);
        e_ = uc  - cc; dvA = fmaf(e_, e_, dvA);
        e_ = ur  - cc; dvA = fmaf(e_, e_, dvA);
        e_ = clm - cc; dvA = fmaf(e_, e_, dvA);
        e_ = crm - cc; dvA = fmaf(e_, e_, dvA);
        e_ = dlm - cc; dvA = fmaf(e_, e_, dvA);
        e_ = dc  - cc; dvA = fmaf(e_, e_, dvA);
        e_ = drm - cc; dvA = fmaf(e_, e_, dvA);

        // --- output row B = h0+1: center dc; taps U=(clm,cc,crm) C=(dlm,drm) D=(el,ec,er)
        float aggB =     p0 * clm;
        aggB = fmaf(p1, cc,  aggB);
        aggB = fmaf(p2, crm, aggB);
        aggB = fmaf(p3, dlm, aggB);
        aggB = fmaf(p4, drm, aggB);
        aggB = fmaf(p5, el,  aggB);
        aggB = fmaf(p6, ec,  aggB);
        aggB = fmaf(p7, er,  aggB);
        s_selT[1][w][q * 16 + ci] = __float2bfloat16(aggB);

        e_ = clm - dc; dvB = fmaf(e_, e_, dvB);
        e_ = cc  - dc; dvB = fmaf(e_, e_, dvB);
        e_ = crm - dc; dvB = fmaf(e_, e_, dvB);
        e_ = dlm - dc; dvB = fmaf(e_, e_, dvB);
        e_ = drm - dc; dvB = fmaf(e_, e_, dvB);
        e_ = el  - dc; dvB = fmaf(e_, e_, dvB);
        e_ = ec  - dc; dvB = fmaf(e_, e_, dvB);
        e_ = er  - dc; dvB = fmaf(e_, e_, dvB);
    }
    s_divp[0][q][w] = dvA;
    s_divp[1][q][w] = dvB;
    __syncthreads();

    // ---- A-fragments early (s_core ready; overlaps mask phase) ----
    const int lane = tid & 63;
    const int wid  = tid >> 6;          // 0..7
    const int o0   = (wid & 3) * 16;    // o-tile
    const int wh   = wid >> 2;          // w-half 0/1 -> 4 w-tiles each
    const int n    = lane & 15;         // col within tile (w), also A-row (o)
    const int quad = lane >> 4;
    const short8 a0 = *(const short8*)&s_core[o0 + n][quad * 8];
    const short8 a1 = *(const short8*)&s_core[o0 + n][quad * 8 + 32];

    // ---- Phase 2: masks for both rows ----
    if (tid < 2 * Wc) {
        const int rr = tid >> 7, ww = tid & (Wc - 1);
        const float div = s_divp[rr][0][ww] + s_divp[rr][1][ww]
                        + s_divp[rr][2][ww] + s_divp[rr][3][ww];
        const bool one = ((div - thr[0]) * scl[0]) > 0.f;  // == sigmoid>0.5
        s_msk[rr][ww] = one ? 1.f : 0.f;
        if (!one) s_any = 1;              // benign LDS race: all write 1
    }
    __syncthreads();

    // ---- Rare path: overwrite masked columns with center ----
    if (s_any) {                          // block-uniform branch
        #pragma unroll
        for (int i = 0; i < 32; ++i) {    // 2*8192 elems / 512 thr
            const int idx = i * 512 + tid;
            const int rr  = idx >> 13;
            const int e2  = idx & 8191;
            const int ww  = e2 & (Wc - 1);
            const int c   = e2 >> 7;
            if (s_msk[rr][ww] == 0.f)
                s_selT[rr][ww][c] =
                    __float2bfloat16(xb[(size_t)c * HWc + rr * Wc + ww]);
        }
        __syncthreads();
    }

    // ---- Phase 3: MFMA GEMM x2 rows: D[o][w] = core[o][c]*sel[c][w], K=64 ----
    float* outb = out + ((size_t)(b * Oc) * Hc + h0) * Wc;

    #pragma unroll
    for (int rr = 0; rr < 2; ++rr) {
        #pragma unroll
        for (int t = 0; t < 4; ++t) {
            const int w0 = (wh * 4 + t) * 16;
            const short8 b0 = *(const short8*)&s_selT[rr][w0 + n][quad * 8];
            const short8 b1 = *(const short8*)&s_selT[rr][w0 + n][quad * 8 + 32];
            floatx4 acc = {0.f, 0.f, 0.f, 0.f};
            acc = __builtin_amdgcn_mfma_f32_16x16x32_bf16(a0, b0, acc, 0, 0, 0);
            acc = __builtin_amdgcn_mfma_f32_16x16x32_bf16(a1, b1, acc, 0, 0, 0);
            #pragma unroll
            for (int r = 0; r < 4; ++r) {
                const int o = o0 + quad * 4 + r;
                outb[(size_t)o * HWc + rr * Wc + w0 + n] = acc[r];
            }
        }
    }
}

extern "C" void kernel_launch(void* const* d_in, const int* in_sizes, int n_in,
                              void* d_out, int out_size, void* d_ws, size_t ws_size,
                              hipStream_t stream) {
    const float* x    = (const float*)d_in[0];
    const float* core = (const float*)d_in[1];
    const float* peri = (const float*)d_in[2];
    const float* thr  = (const float*)d_in[3];
    const float* scl  = (const float*)d_in[4];
    float* out = (float*)d_out;

    spconv_kernel<<<dim3(Bc * Hc / 2), dim3(512), 0, stream>>>(
        x, core, peri, thr, scl, out);
}

// Round 4
// 98.171 us; speedup vs baseline: 1.2841x; 1.0237x over previous
//
#include <hip/hip_runtime.h>
#include <hip/hip_bf16.h>

// B=8, C=64, O=64, H=W=128, stride=1, pad=1, 3x3.
constexpr int Bc = 8;
constexpr int Cc = 64;
constexpr int Oc = 64;
constexpr int Hc = 128;
constexpr int Wc = 128;
constexpr int HWc = Hc * Wc;
constexpr int CP = 72;   // padded LDS row stride bf16 (144 B = 16B-aligned)

typedef __attribute__((ext_vector_type(8))) short short8;   // 8 x bf16
typedef __attribute__((ext_vector_type(4))) float floatx4;
typedef __attribute__((ext_vector_type(2))) float floatx2;

__device__ __forceinline__ float bperm(int idx4, float v) {
    return __int_as_float(__builtin_amdgcn_ds_bpermute(idx4, __float_as_int(v)));
}
// packed f32x2 -> bf16x2 (RNE), lo -> bits[15:0]
__device__ __forceinline__ unsigned cvt_pk_bf16(float lo, float hi) {
    unsigned r;
    asm("v_cvt_pk_bf16_f32 %0, %1, %2" : "=v"(r) : "v"(lo), "v"(hi));
    return r;
}

// v5: 2-row blocks (v4) + float2/2-pixel lanes + ds_bpermute horizontal taps.
// Each wave spans the full 128-wide row and owns 8 channels: per channel only
// 4 float2 loads (rows h0-1..h0+2, columns 2l..2l+1); w-1/w+1 taps come from
// lane shuffles (wave-internal; lane0/63 edge-masked). VMEM instrs/thread
// 192 -> 32, L1 tap bytes 201 -> 67 MB. selT stored with w-parity-split
// physical rows (phys = (w>>1)|((w&1)<<6)) so LDS writes keep the
// measured-benign stride; GEMM reads index phys rows (144B stride keeps
// b128 reads aligned). XCD remap + s_any fixup skip kept (measured wins).
__global__ __launch_bounds__(512, 4) void spconv_kernel(
    const float* __restrict__ x, const float* __restrict__ core,
    const float* __restrict__ peri, const float* __restrict__ thr,
    const float* __restrict__ scl, float* __restrict__ out)
{
    __shared__ __hip_bfloat16 s_selT[2][Wc][CP];  // [row][physw][c] 36864 B
    __shared__ __hip_bfloat16 s_core[Oc][CP];     //                  9216 B
    __shared__ float s_divp[2][8][Wc];            //                  8192 B
    __shared__ float s_msk[2][Wc];                //                  1024 B
    __shared__ int   s_any;

    const int tid = threadIdx.x;
    const int l   = tid & 63;                   // lane
    const int wv  = tid >> 6;                   // wave 0..7
    const int b   = blockIdx.x & 7;             // one image per XCD
    const int hp  = blockIdx.x >> 3;            // row pair 0..63
    const int h0  = hp * 2;

    if (tid == 0) s_any = 0;

    // ---- Phase 0: core -> bf16 LDS (float4 loads, packed writes) ----
    #pragma unroll
    for (int i = 0; i < 2; ++i) {
        const int idx = (i * 512 + tid) * 4;    // 4096 floats total
        const floatx4 v = *(const floatx4*)(core + idx);
        unsigned* dst = (unsigned*)&s_core[idx >> 6][idx & 63];
        dst[0] = cvt_pk_bf16(v.x, v.y);
        dst[1] = cvt_pk_bf16(v.z, v.w);
    }

    // ---- Phase 1: taps. Lane owns pixels w=2l,2l+1; wave owns 8 channels ----
    const int upIdx = ((l - 1) & 63) << 2;      // bperm byte index: lane l-1
    const int dnIdx = ((l + 1) & 63) << 2;      // lane l+1
    const float lzf = (l == 0)  ? 0.f : 1.f;    // w=0 left pad
    const float rzf = (l == 63) ? 0.f : 1.f;    // w=127 right pad
    const float mUf = (h0 > 0) ? 1.f : 0.f;
    const float mDf = (h0 < Hc - 2) ? 1.f : 0.f;
    const int   dU  = (h0 > 0) ? -Wc : 0;          // clamped row offsets
    const int   dD2 = (h0 < Hc - 2) ? 2 * Wc : Wc;

    const float p0 = peri[0], p1 = peri[1], p2 = peri[2], p3 = peri[3];
    const float p4 = peri[4], p5 = peri[5], p6 = peri[6], p7 = peri[7];

    const float* xw = x + (size_t)b * Cc * HWc + (size_t)h0 * Wc + 2 * l;
    const float* xb = x + (size_t)b * Cc * HWc + (size_t)h0 * Wc;  // fixup base

    float dAlo = 0.f, dAhi = 0.f, dBlo = 0.f, dBhi = 0.f;

// PROC: one channel. RM/R0/R1/R2 = rows h0-1..h0+2 (vert pre-masked), K = 0/1
// slot in the channel pair. Produces 4 agg values, accumulates 4 div sums.
#define PROC(RM, R0, R1, R2, K) do {                                          \
    const float rmL = lzf * bperm(upIdx, RM.y);                               \
    const float r0L = lzf * bperm(upIdx, R0.y);                               \
    const float r1L = lzf * bperm(upIdx, R1.y);                               \
    const float r2L = lzf * bperm(upIdx, R2.y);                               \
    const float rmR = rzf * bperm(dnIdx, RM.x);                               \
    const float r0R = rzf * bperm(dnIdx, R0.x);                               \
    const float r1R = rzf * bperm(dnIdx, R1.x);                               \
    const float r2R = rzf * bperm(dnIdx, R2.x);                               \
    { const float t = R0.x;  /* row A, pixel lo (w=2l) */                     \
      float a = p0 * rmL; a = fmaf(p1, RM.x, a); a = fmaf(p2, RM.y, a);       \
      a = fmaf(p3, r0L, a); a = fmaf(p4, R0.y, a);                            \
      a = fmaf(p5, r1L, a); a = fmaf(p6, R1.x, a); a = fmaf(p7, R1.y, a);     \
      aAlo[K] = a; float e;                                                   \
      e = rmL  - t; dAlo = fmaf(e, e, dAlo); e = RM.x - t; dAlo = fmaf(e, e, dAlo); \
      e = RM.y - t; dAlo = fmaf(e, e, dAlo); e = r0L  - t; dAlo = fmaf(e, e, dAlo); \
      e = R0.y - t; dAlo = fmaf(e, e, dAlo); e = r1L  - t; dAlo = fmaf(e, e, dAlo); \
      e = R1.x - t; dAlo = fmaf(e, e, dAlo); e = R1.y - t; dAlo = fmaf(e, e, dAlo); } \
    { const float t = R0.y;  /* row A, pixel hi (w=2l+1) */                   \
      float a = p0 * RM.x; a = fmaf(p1, RM.y, a); a = fmaf(p2, rmR, a);       \
      a = fmaf(p3, R0.x, a); a = fmaf(p4, r0R, a);                            \
      a = fmaf(p5, R1.x, a); a = fmaf(p6, R1.y, a); a = fmaf(p7, r1R, a);     \
      aAhi[K] = a; float e;                                                   \
      e = RM.x - t; dAhi = fmaf(e, e, dAhi); e = RM.y - t; dAhi = fmaf(e, e, dAhi); \
      e = rmR  - t; dAhi = fmaf(e, e, dAhi); e = R0.x - t; dAhi = fmaf(e, e, dAhi); \
      e = r0R  - t; dAhi = fmaf(e, e, dAhi); e = R1.x - t; dAhi = fmaf(e, e, dAhi); \
      e = R1.y - t; dAhi = fmaf(e, e, dAhi); e = r1R  - t; dAhi = fmaf(e, e, dAhi); } \
    { const float t = R1.x;  /* row B, pixel lo */                            \
      float a = p0 * r0L; a = fmaf(p1, R0.x, a); a = fmaf(p2, R0.y, a);       \
      a = fmaf(p3, r1L, a); a = fmaf(p4, R1.y, a);                            \
      a = fmaf(p5, r2L, a); a = fmaf(p6, R2.x, a); a = fmaf(p7, R2.y, a);     \
      aBlo[K] = a; float e;                                                   \
      e = r0L  - t; dBlo = fmaf(e, e, dBlo); e = R0.x - t; dBlo = fmaf(e, e, dBlo); \
      e = R0.y - t; dBlo = fmaf(e, e, dBlo); e = r1L  - t; dBlo = fmaf(e, e, dBlo); \
      e = R1.y - t; dBlo = fmaf(e, e, dBlo); e = r2L  - t; dBlo = fmaf(e, e, dBlo); \
      e = R2.x - t; dBlo = fmaf(e, e, dBlo); e = R2.y - t; dBlo = fmaf(e, e, dBlo); } \
    { const float t = R1.y;  /* row B, pixel hi */                            \
      float a = p0 * R0.x; a = fmaf(p1, R0.y, a); a = fmaf(p2, r0R, a);       \
      a = fmaf(p3, R1.x, a); a = fmaf(p4, r1R, a);                            \
      a = fmaf(p5, R2.x, a); a = fmaf(p6, R2.y, a); a = fmaf(p7, r2R, a);     \
      aBhi[K] = a; float e;                                                   \
      e = R0.x - t; dBhi = fmaf(e, e, dBhi); e = R0.y - t; dBhi = fmaf(e, e, dBhi); \
      e = r0R  - t; dBhi = fmaf(e, e, dBhi); e = R1.x - t; dBhi = fmaf(e, e, dBhi); \
      e = r1R  - t; dBhi = fmaf(e, e, dBhi); e = R2.x - t; dBhi = fmaf(e, e, dBhi); \
      e = R2.y - t; dBhi = fmaf(e, e, dBhi); e = r2R  - t; dBhi = fmaf(e, e, dBhi); } \
} while (0)

    #pragma unroll 2
    for (int j = 0; j < 4; ++j) {
        const int c0 = wv * 8 + 2 * j;          // channel pair c0, c0+1
        const float* b0p = xw + (size_t)c0 * HWc;
        const float* b1p = b0p + HWc;

        floatx2 rm0 = *(const floatx2*)(b0p + dU);
        floatx2 r00 = *(const floatx2*)(b0p);
        floatx2 r10 = *(const floatx2*)(b0p + Wc);
        floatx2 r20 = *(const floatx2*)(b0p + dD2);
        floatx2 rm1 = *(const floatx2*)(b1p + dU);
        floatx2 r01 = *(const floatx2*)(b1p);
        floatx2 r11 = *(const floatx2*)(b1p + Wc);
        floatx2 r21 = *(const floatx2*)(b1p + dD2);
        rm0 *= mUf; r20 *= mDf; rm1 *= mUf; r21 *= mDf;   // zero padded rows

        float aAlo[2], aAhi[2], aBlo[2], aBhi[2];
        PROC(rm0, r00, r10, r20, 0);
        PROC(rm1, r01, r11, r21, 1);

        // packed bf16x2 writes; phys rows: w=2l -> l, w=2l+1 -> 64+l
        *(unsigned*)&s_selT[0][l]      [c0] = cvt_pk_bf16(aAlo[0], aAlo[1]);
        *(unsigned*)&s_selT[0][64 + l] [c0] = cvt_pk_bf16(aAhi[0], aAhi[1]);
        *(unsigned*)&s_selT[1][l]      [c0] = cvt_pk_bf16(aBlo[0], aBlo[1]);
        *(unsigned*)&s_selT[1][64 + l] [c0] = cvt_pk_bf16(aBhi[0], aBhi[1]);
    }
#undef PROC

    {   // div partials (logical w indexing)
        floatx2 da = {dAlo, dAhi}, db = {dBlo, dBhi};
        *(floatx2*)&s_divp[0][wv][2 * l] = da;
        *(floatx2*)&s_divp[1][wv][2 * l] = db;
    }
    __syncthreads();

    // ---- A-fragments early (overlaps mask phase) ----
    const int o0   = (wv & 3) * 16;
    const int wh   = wv >> 2;
    const int n    = l & 15;
    const int quad = l >> 4;
    const short8 a0 = *(const short8*)&s_core[o0 + n][quad * 8];
    const short8 a1 = *(const short8*)&s_core[o0 + n][quad * 8 + 32];

    // ---- Phase 2: masks ----
    if (tid < 2 * Wc) {
        const int rr = tid >> 7, ww = tid & (Wc - 1);
        float dv = s_divp[rr][0][ww];
        #pragma unroll
        for (int g = 1; g < 8; ++g) dv += s_divp[rr][g][ww];
        const bool one = ((dv - thr[0]) * scl[0]) > 0.f;   // == sigmoid>0.5
        s_msk[rr][ww] = one ? 1.f : 0.f;
        if (!one) s_any = 1;              // benign race: all write 1
    }
    __syncthreads();

    // ---- Rare path: overwrite masked columns with center ----
    if (s_any) {                          // block-uniform branch
        #pragma unroll
        for (int i = 0; i < 32; ++i) {    // 2*8192 elems / 512 thr
            const int idx = i * 512 + tid;
            const int rr  = idx >> 13;
            const int e2  = idx & 8191;
            const int p   = e2 & (Wc - 1);                   // phys row
            const int c   = e2 >> 7;
            const int ww  = ((p & 63) << 1) | (p >> 6);      // logical w
            if (s_msk[rr][ww] == 0.f)
                s_selT[rr][p][c] =
                    __float2bfloat16(xb[(size_t)c * HWc + rr * Wc + ww]);
        }
        __syncthreads();
    }

    // ---- Phase 3: MFMA GEMM x2 rows: D[o][w] = core[o][c]*sel[c][w] ----
    float* outb = out + ((size_t)(b * Oc) * Hc + h0) * Wc;

    #pragma unroll
    for (int rr = 0; rr < 2; ++rr) {
        #pragma unroll
        for (int t = 0; t < 4; ++t) {
            const int w0   = (wh * 4 + t) * 16;
            const int wlog = w0 + n;
            const int pr   = ((wlog >> 1) & 63) | ((wlog & 1) << 6);
            const short8 b0 = *(const short8*)&s_selT[rr][pr][quad * 8];
            const short8 b1 = *(const short8*)&s_selT[rr][pr][quad * 8 + 32];
            floatx4 acc = {0.f, 0.f, 0.f, 0.f};
            acc = __builtin_amdgcn_mfma_f32_16x16x32_bf16(a0, b0, acc, 0, 0, 0);
            acc = __builtin_amdgcn_mfma_f32_16x16x32_bf16(a1, b1, acc, 0, 0, 0);
            #pragma unroll
            for (int r = 0; r < 4; ++r) {
                const int o = o0 + quad * 4 + r;
                outb[(size_t)o * HWc + rr * Wc + w0 + n] = acc[r];
            }
        }
    }
}

extern "C" void kernel_launch(void* const* d_in, const int* in_sizes, int n_in,
                              void* d_out, int out_size, void* d_ws, size_t ws_size,
                              hipStream_t stream) {
    const float* x    = (const float*)d_in[0];
    const float* core = (const float*)d_in[1];
    const float* peri = (const float*)d_in[2];
    const float* thr  = (const float*)d_in[3];
    const float* scl  = (const float*)d_in[4];
    float* out = (float*)d_out;

    spconv_kernel<<<dim3(Bc * Hc / 2), dim3(512), 0, stream>>>(
        x, core, peri, thr, scl, out);
}